// Round 3
// baseline (823.803 us; speedup 1.0000x reference)
//
#include <hip/hip_runtime.h>

// Fixed dataset: N=100000 nodes, E=1.6M edges, C=32 feats, G=256 graphs.
// ONE persistent kernel (512 blocks x 512 thr, co-resident via launch_bounds(512,4))
// with device-scope software grid barriers between phases:
//   Z: zero wcur/gsum | B: bucket edges->windows | W: window (norm,CSR,bf16 prep)
//   H1: hop A->B | H2: hop B->A | H3F: hop + GCN linear + ReLU + graph-pool | HD: head
constexpr int NW    = 391;   // nodes per window -> W=256 windows
constexpr int CH2   = 3200;  // edges per bucketing chunk -> 500 chunks
constexpr int CAP_B = 8192;  // packed-edge capacity per window (E/W=6250, sigma~79)
constexpr int CAP_C = 10240; // padded-csr capacity per window (max ~9400)
constexpr int NBLK  = 512;   // persistent grid: 2 blocks/CU on 256 CUs
constexpr int BT    = 512;
constexpr unsigned MAGIC = 0x1b9d2f47u;
// packed edge: (local_dst << 17) | src   (src < 2^17, local_dst < 512)

// ---- bf16 helpers (RNE) ----
__device__ __forceinline__ unsigned bf16_rne(float x) {
    unsigned u = __float_as_uint(x);
    u += 0x7fffu + ((u >> 16) & 1u);
    return u >> 16;
}
__device__ __forceinline__ unsigned pack2(float even, float odd) {
    return bf16_rne(even) | (bf16_rne(odd) << 16);
}
__device__ __forceinline__ float lo_f(unsigned u) { return __uint_as_float(u << 16); }
__device__ __forceinline__ float hi_f(unsigned u) { return __uint_as_float(u & 0xffff0000u); }

// ---- device-wide barrier: ctrl[0]=init_flag, ctrl[1]=arrive, ctrl[2]=generation ----
__device__ __forceinline__ void gbar(int* ctrl) {
    __syncthreads();
    if (threadIdx.x == 0) {
        __threadfence();
        int g = __hip_atomic_load(&ctrl[2], __ATOMIC_ACQUIRE, __HIP_MEMORY_SCOPE_AGENT);
        int a = __hip_atomic_fetch_add(&ctrl[1], 1, __ATOMIC_ACQ_REL, __HIP_MEMORY_SCOPE_AGENT);
        if (a == (int)gridDim.x - 1) {
            __hip_atomic_store(&ctrl[1], 0, __ATOMIC_RELAXED, __HIP_MEMORY_SCOPE_AGENT);
            __hip_atomic_store(&ctrl[2], g + 1, __ATOMIC_RELEASE, __HIP_MEMORY_SCOPE_AGENT);
        } else {
            while (__hip_atomic_load(&ctrl[2], __ATOMIC_ACQUIRE, __HIP_MEMORY_SCOPE_AGENT) == g)
                __builtin_amdgcn_s_sleep(1);
        }
        __threadfence();
    }
    __syncthreads();
}

// ---- shared gather core: 4 lanes/node, uint4/lane, 16 outstanding gathers ----
// Edge lists padded to multiples of 8; ascending edge order (bitwise-stable sums).
__device__ __forceinline__ void gather_sum(const uint4* __restrict__ tab,
                                           const int* __restrict__ csr,
                                           int2 be, int l, float* a) {
    int k = be.x;
    for (; k + 16 <= be.y; k += 16) {
        int e0 = csr[k + l], e1 = csr[k + 4 + l], e2 = csr[k + 8 + l], e3 = csr[k + 12 + l];
        uint4 u[16];
#pragma unroll
        for (int j = 0; j < 4; ++j) u[j]      = tab[(size_t)__shfl(e0, j, 4) * 4 + l];
#pragma unroll
        for (int j = 0; j < 4; ++j) u[4 + j]  = tab[(size_t)__shfl(e1, j, 4) * 4 + l];
#pragma unroll
        for (int j = 0; j < 4; ++j) u[8 + j]  = tab[(size_t)__shfl(e2, j, 4) * 4 + l];
#pragma unroll
        for (int j = 0; j < 4; ++j) u[12 + j] = tab[(size_t)__shfl(e3, j, 4) * 4 + l];
#pragma unroll
        for (int j = 0; j < 16; ++j) {
            a[0] += lo_f(u[j].x); a[1] += hi_f(u[j].x);
            a[2] += lo_f(u[j].y); a[3] += hi_f(u[j].y);
            a[4] += lo_f(u[j].z); a[5] += hi_f(u[j].z);
            a[6] += lo_f(u[j].w); a[7] += hi_f(u[j].w);
        }
    }
    if (k < be.y) { // one remaining 8-group
        int e0 = csr[k + l], e1 = csr[k + 4 + l];
        uint4 u[8];
#pragma unroll
        for (int j = 0; j < 4; ++j) u[j]     = tab[(size_t)__shfl(e0, j, 4) * 4 + l];
#pragma unroll
        for (int j = 0; j < 4; ++j) u[4 + j] = tab[(size_t)__shfl(e1, j, 4) * 4 + l];
#pragma unroll
        for (int j = 0; j < 8; ++j) {
            a[0] += lo_f(u[j].x); a[1] += hi_f(u[j].x);
            a[2] += lo_f(u[j].y); a[3] += hi_f(u[j].y);
            a[4] += lo_f(u[j].z); a[5] += hi_f(u[j].z);
            a[6] += lo_f(u[j].w); a[7] += hi_f(u[j].w);
        }
    }
}

__device__ __forceinline__ void hop_pass(const uint4* __restrict__ tab,
                                         const float* __restrict__ norm,
                                         const int2* __restrict__ rng,
                                         const int* __restrict__ csr,
                                         uint4* __restrict__ outb, int N, int t) {
    int l = t & 3;
    int stride = (int)((gridDim.x * BT) >> 2);
    for (int group = (int)((blockIdx.x * BT + t) >> 2); group <= N; group += stride) {
        uint4 sv = tab[(size_t)group * 4 + l]; // self term
        float a[8] = {lo_f(sv.x), hi_f(sv.x), lo_f(sv.y), hi_f(sv.y),
                      lo_f(sv.z), hi_f(sv.z), lo_f(sv.w), hi_f(sv.w)};
        gather_sum(tab, csr, rng[group], l, a);
        float n = norm[group], sc = n * n;
        outb[(size_t)group * 4 + l] =
            make_uint4(pack2(a[0] * sc, a[1] * sc), pack2(a[2] * sc, a[3] * sc),
                       pack2(a[4] * sc, a[5] * sc), pack2(a[6] * sc, a[7] * sc));
    }
}

__global__ __launch_bounds__(BT, 4) void k_all(
    const float4* __restrict__ x4,
    const int* __restrict__ srcp, const int* __restrict__ dstp,
    const int* __restrict__ batch,
    const float* __restrict__ gw, const float* __restrict__ gb,
    const float* __restrict__ w1, const float* __restrict__ b1,
    const float* __restrict__ w2, const float* __restrict__ b2,
    float* __restrict__ out, int* ctrl,
    int* __restrict__ wcur, float* __restrict__ gsum,
    int* __restrict__ packed, int* __restrict__ csr,
    int2* __restrict__ rng, float* __restrict__ norm,
    uint2* __restrict__ hb, uint2* __restrict__ hb2,
    int N, int E, int G, int W, int nchunks) {
    // bucket
    __shared__ int sh_h[256];
    __shared__ int sh_base[256];
    // window
    __shared__ int hist[NW];
    __shared__ float snorm[NW];
    __shared__ int pend[NW];
    __shared__ int cur[NW];
    __shared__ int wpart[8];
    // feat
    __shared__ __align__(16) float wT[32][64];
    __shared__ float bsx[64];
    __shared__ float accw[8][64];
    // head
    __shared__ float havg[64];
    __shared__ float h1s[32];
    __shared__ int se[2];

    int t = threadIdx.x;
    int bid = blockIdx.x;

    // ---- init handshake (poison-tolerant; gen needs no reset, bar self-restores) ----
    if (t == 0) {
        if (bid == 0) {
            if (__hip_atomic_load(&ctrl[0], __ATOMIC_ACQUIRE, __HIP_MEMORY_SCOPE_AGENT) != (int)MAGIC) {
                __hip_atomic_store(&ctrl[1], 0, __ATOMIC_RELAXED, __HIP_MEMORY_SCOPE_AGENT);
                __threadfence();
                __hip_atomic_store(&ctrl[0], (int)MAGIC, __ATOMIC_RELEASE, __HIP_MEMORY_SCOPE_AGENT);
            }
        } else {
            while (__hip_atomic_load(&ctrl[0], __ATOMIC_ACQUIRE, __HIP_MEMORY_SCOPE_AGENT) != (int)MAGIC)
                __builtin_amdgcn_s_sleep(1);
        }
    }
    __syncthreads();

    // ---- phase Z: zero wcur + gsum ----
    {
        int gt = bid * BT + t, NT = NBLK * BT;
        for (int i = gt; i < 256; i += NT) wcur[i] = 0;
        for (int i = gt; i < G * 64; i += NT) gsum[i] = 0.f;
    }
    gbar(ctrl);

    // ---- phase B: bucket edges into per-window packed slices ----
    for (int cb = bid; cb < nchunks; cb += gridDim.x) {
        if (t < 256) sh_h[t] = 0;
        __syncthreads();
        int b0 = cb * CH2;
        int cnt = min(CH2, E - b0);
        if (cnt == CH2) { // full chunk: int4 paths
            const int4* d4 = (const int4*)(dstp + b0);
            for (int i = t; i < CH2 / 4; i += BT) {
                int4 v = d4[i];
                atomicAdd(&sh_h[v.x / NW], 1); atomicAdd(&sh_h[v.y / NW], 1);
                atomicAdd(&sh_h[v.z / NW], 1); atomicAdd(&sh_h[v.w / NW], 1);
            }
        } else {
            for (int i = t; i < cnt; i += BT) atomicAdd(&sh_h[dstp[b0 + i] / NW], 1);
        }
        __syncthreads();
        if (t < 256) { sh_base[t] = atomicAdd(&wcur[t], sh_h[t]); sh_h[t] = 0; }
        __syncthreads();
        if (cnt == CH2) {
            const int4* d4 = (const int4*)(dstp + b0);
            const int4* s4 = (const int4*)(srcp + b0);
            for (int i = t; i < CH2 / 4; i += BT) { // L1/L2-hot re-read
                int4 dv = d4[i];
                int4 sv = s4[i];
                int da[4] = {dv.x, dv.y, dv.z, dv.w};
                int sa[4] = {sv.x, sv.y, sv.z, sv.w};
#pragma unroll
                for (int j = 0; j < 4; ++j) {
                    int w = da[j] / NW;
                    int ld = da[j] - w * NW;
                    int r = atomicAdd(&sh_h[w], 1);
                    int pos = sh_base[w] + r;
                    if (pos < CAP_B) packed[w * CAP_B + pos] = (ld << 17) | sa[j];
                }
            }
        } else {
            for (int i = t; i < cnt; i += BT) {
                int d = dstp[b0 + i];
                int s = srcp[b0 + i];
                int w = d / NW;
                int ld = d - w * NW;
                int r = atomicAdd(&sh_h[w], 1);
                int pos = sh_base[w] + r;
                if (pos < CAP_B) packed[w * CAP_B + pos] = (ld << 17) | s;
            }
        }
        __syncthreads(); // before sh_h reuse in next chunk
    }
    gbar(ctrl);

    // ---- phase W: per-window degree->norm, scan, CSR fill, bf16 prep ----
    for (int w = bid; w < W; w += gridDim.x) {
        int lo = w * NW, nwn = min(NW, N - lo);
        for (int i = t; i < NW; i += BT) hist[i] = 0;
        __syncthreads();
        int cnt = min(wcur[w], CAP_B);
        const int* pk = packed + (size_t)w * CAP_B;
        for (int e = t; e < cnt; e += BT) atomicAdd(&hist[pk[e] >> 17], 1);
        __syncthreads();
        int d = (t < nwn) ? hist[t] : 0;
        float nv = rsqrtf((float)(d + 1));
        if (t < nwn) { snorm[t] = nv; norm[lo + t] = nv; }
        int pd = (t < nwn) ? ((d + 7) & ~7) : 0; // pad node list to multiple of 8
        int lane = t & 63, wid = t >> 6;
        int v = pd;
#pragma unroll
        for (int s = 1; s < 64; s <<= 1) {
            int u = __shfl_up(v, s, 64);
            if (lane >= s) v += u;
        }
        if (lane == 63) wpart[wid] = v;
        __syncthreads();
        if (t < 8) {
            int z = wpart[t];
#pragma unroll
            for (int s = 1; s < 8; s <<= 1) {
                int u = __shfl_up(z, s, 8);
                if (t >= s) z += u;
            }
            wpart[t] = z;
        }
        __syncthreads();
        int incl = v + (wid ? wpart[wid - 1] : 0);
        int base = w * CAP_C;
        int cend = base + incl;
        if (t < nwn) {
            rng[lo + t] = make_int2(cend - pd, cend);
            pend[t] = cend;
            cur[t] = cend - pd;
        }
        if (w == W - 1 && t == 0) { norm[N] = 1.f; rng[N] = make_int2(0, 0); } // sentinel
        __syncthreads();
        for (int e = t; e < cnt; e += BT) {
            int p = pk[e];
            int pos = atomicAdd(&cur[p >> 17], 1);
            csr[pos] = p & 0x1FFFF;
        }
        __syncthreads();
        if (t < nwn) {
            for (int pos = cur[t]; pos < pend[t]; ++pos) csr[pos] = N; // sentinel padding
        }
        // fused prep: hs = norm*x rows in bf16 for this window's nodes
        for (int idx = t; idx < nwn * 8; idx += BT) {
            int node = idx >> 3, q = idx & 7;
            float nn = snorm[node];
            float4 vx = x4[(size_t)(lo + node) * 8 + q];
            hb[(size_t)(lo + node) * 8 + q] =
                make_uint2(pack2(vx.x * nn, vx.y * nn), pack2(vx.z * nn, vx.w * nn));
        }
        if (w == W - 1 && t < 8) hb[(size_t)N * 8 + t] = make_uint2(0u, 0u); // sentinel row
        __syncthreads();
    }
    gbar(ctrl);

    // ---- phase H1: hop A -> B ----
    hop_pass((const uint4*)hb, norm, rng, csr, (uint4*)hb2, N, t);
    gbar(ctrl);
    // ---- phase H2: hop B -> A ----
    hop_pass((const uint4*)hb2, norm, rng, csr, (uint4*)hb, N, t);
    gbar(ctrl);

    // ---- phase H3F: hop + GCN linear + ReLU + per-graph pool ----
    {
        int c = t & 63, w8 = t >> 6;
#pragma unroll
        for (int iter = 0; iter < 4; ++iter) { // swizzled wT init, 8 waves
            int k = iter * 8 + w8;
            wT[k][c] = gw[c * 32 + k];
        }
        if (t < 64) bsx[t] = gb[t];
        __syncthreads();
        const uint4* tab = (const uint4*)hb;
        int l = t & 3;
        int wid = t >> 6;
        const int STRIDE = (NBLK * BT) >> 2;
        int nIt = (N + STRIDE) / STRIDE; // ceil((N+1)/STRIDE), uniform
        for (int it = 0; it < nIt; ++it) {
            int group = ((bid * BT + t) >> 2) + it * STRIDE;
            float o[16];
#pragma unroll
            for (int cc = 0; cc < 16; ++cc) o[cc] = 0.f;
            int gmy = 0x7fffffff;
            if (group < N) { // uniform per 4-lane cluster -> shfl safe
                uint4 sv = tab[(size_t)group * 4 + l];
                float a[8] = {lo_f(sv.x), hi_f(sv.x), lo_f(sv.y), hi_f(sv.y),
                              lo_f(sv.z), hi_f(sv.z), lo_f(sv.w), hi_f(sv.w)};
                gather_sum(tab, csr, rng[group], l, a);
                float n = norm[group];
#pragma unroll
                for (int j = 0; j < 8; ++j) a[j] *= n;
                gmy = batch[group];
                float dd[16];
#pragma unroll
                for (int cc = 0; cc < 16; ++cc) dd[cc] = bsx[l * 16 + cc];
#pragma unroll
                for (int k = 0; k < 32; ++k) {
                    float hk = __shfl(a[k & 7], k >> 3, 4); // feature k from sibling lane
                    const float4* wv = (const float4*)&wT[k][l * 16];
                    float4 w0 = wv[0], w1v = wv[1], w2v = wv[2], w3v = wv[3];
                    dd[0]  += hk * w0.x;  dd[1]  += hk * w0.y;  dd[2]  += hk * w0.z;  dd[3]  += hk * w0.w;
                    dd[4]  += hk * w1v.x; dd[5]  += hk * w1v.y; dd[6]  += hk * w1v.z; dd[7]  += hk * w1v.w;
                    dd[8]  += hk * w2v.x; dd[9]  += hk * w2v.y; dd[10] += hk * w2v.z; dd[11] += hk * w2v.w;
                    dd[12] += hk * w3v.x; dd[13] += hk * w3v.y; dd[14] += hk * w3v.z; dd[15] += hk * w3v.w;
                }
#pragma unroll
                for (int cc = 0; cc < 16; ++cc) o[cc] = fmaxf(dd[cc], 0.f);
            }
            int n0 = bid * (BT / 4) + it * STRIDE;
            int g0 = batch[min(n0, N - 1)];
            int g1 = batch[min(n0 + BT / 4 - 1, N - 1)];
            bool leader = (t & 0x3C) == 0;
            for (int g = g0; g <= g1; ++g) {
                float vv[16];
#pragma unroll
                for (int cc = 0; cc < 16; ++cc) {
                    float val = (gmy == g) ? o[cc] : 0.f;
                    val += __shfl_xor(val, 4, 64);
                    val += __shfl_xor(val, 8, 64);
                    val += __shfl_xor(val, 16, 64);
                    val += __shfl_xor(val, 32, 64);
                    vv[cc] = val;
                }
                if (leader) {
#pragma unroll
                    for (int cc = 0; cc < 16; ++cc) accw[wid][l * 16 + cc] = vv[cc];
                }
                __syncthreads();
                if (t < 64) {
                    float s = accw[0][t] + accw[1][t] + accw[2][t] + accw[3][t]
                            + accw[4][t] + accw[5][t] + accw[6][t] + accw[7][t];
                    if (s != 0.f) atomicAdd(&gsum[(size_t)g * 64 + t], s);
                }
                __syncthreads();
            }
        }
    }
    gbar(ctrl);

    // ---- phase HD: mean + classifier head ----
    for (int g = bid; g < G; g += gridDim.x) {
        if (t < 2) { // lower_bound(batch, g) / lower_bound(batch, g+1)
            int target = g + t;
            int lo2 = 0, hi2 = N;
            while (lo2 < hi2) { int mid = (lo2 + hi2) >> 1; if (batch[mid] < target) lo2 = mid + 1; else hi2 = mid; }
            se[t] = lo2;
        }
        __syncthreads();
        int cnt = se[1] - se[0];
        float inv = 1.f / (float)(cnt > 0 ? cnt : 1);
        if (t < 64) havg[t] = gsum[(size_t)g * 64 + t] * inv;
        __syncthreads();
        if (t < 32) {
            float d = b1[t];
#pragma unroll
            for (int k = 0; k < 64; ++k) d += havg[k] * w1[t * 64 + k];
            h1s[t] = fmaxf(d, 0.f);
        }
        __syncthreads();
        if (t < 16) {
            float d = b2[t];
#pragma unroll
            for (int j = 0; j < 32; ++j) d += h1s[j] * w2[t * 32 + j];
            out[g * 16 + t] = d;
        }
        __syncthreads();
    }
}

// ---------------- launch ----------------

extern "C" void kernel_launch(void* const* d_in, const int* in_sizes, int n_in,
                              void* d_out, int out_size, void* d_ws, size_t ws_size,
                              hipStream_t stream) {
    const float* x     = (const float*)d_in[0];
    const int*   ei    = (const int*)d_in[1];
    const int*   batch = (const int*)d_in[2];
    const float* gw    = (const float*)d_in[3];
    const float* gb    = (const float*)d_in[4];
    const float* w1    = (const float*)d_in[5];
    const float* b1    = (const float*)d_in[6];
    const float* w2    = (const float*)d_in[7];
    const float* b2    = (const float*)d_in[8];
    float* out = (float*)d_out;

    int N = in_sizes[2];
    int E = in_sizes[1] / 2;
    int G = out_size / 16;
    const int* srcp = ei;
    const int* dstp = ei + E;

    int W  = (N + NW - 1) / NW;     // 256
    int nchunks = (E + CH2 - 1) / CH2; // 500

    char* ws = (char*)d_ws;
    size_t off = 0;
    auto alloc = [&](size_t bytes) -> void* {
        void* p = ws + off;
        off += (bytes + 255) & ~(size_t)255;
        return p;
    };
    int*   ctrl   = (int*)alloc(256);                            // barrier state
    int*   wcur   = (int*)alloc(256 * 4);
    float* gsum   = (float*)alloc((size_t)G * 64 * 4);
    int*   packed = (int*)alloc((size_t)W * CAP_B * 4);          // 8 MB
    int*   csr    = (int*)alloc((size_t)W * CAP_C * 4);          // 10.5 MB
    int2*  rng    = (int2*)alloc((size_t)(N + 1) * 8);
    float* norm   = (float*)alloc((size_t)(N + 1) * 4);
    uint2* hbA    = (uint2*)alloc((size_t)(N + 1) * 64);         // bf16 table A
    uint2* hbB    = (uint2*)alloc((size_t)(N + 1) * 64);         // bf16 table B

    k_all<<<NBLK, BT, 0, stream>>>((const float4*)x, srcp, dstp, batch,
                                   gw, gb, w1, b1, w2, b2, out, ctrl,
                                   wcur, gsum, packed, csr, rng, norm,
                                   hbA, hbB, N, E, G, W, nchunks);
}

// Round 4
// 200.580 us; speedup vs baseline: 4.1071x; 4.1071x over previous
//
#include <hip/hip_runtime.h>

// Fixed dataset: N=100000 nodes, E=1.6M edges, C=32 feats, G=256 graphs.
constexpr int NW    = 391;   // nodes per window -> W=256 windows
constexpr int CH    = 6400;  // edges per bucketing chunk -> NB=250 blocks
constexpr int CAP_B = 8192;  // packed-edge capacity per window (E/W=6250, sigma~79)
constexpr int CAP_C = 10240; // padded-csr capacity per window (max ~9400)
// packed edge: (local_dst << 17) | src   (src < 2^17, local_dst < 512)

// ---- bf16 helpers (RNE) ----
__device__ __forceinline__ unsigned bf16_rne(float x) {
    unsigned u = __float_as_uint(x);
    u += 0x7fffu + ((u >> 16) & 1u);
    return u >> 16;
}
__device__ __forceinline__ unsigned pack2(float even, float odd) {
    return bf16_rne(even) | (bf16_rne(odd) << 16);
}
__device__ __forceinline__ float lo_f(unsigned u) { return __uint_as_float(u << 16); }
__device__ __forceinline__ float hi_f(unsigned u) { return __uint_as_float(u & 0xffff0000u); }

// ---------------- single-pass bucket: edges -> fixed per-window slices ----------------

__global__ __launch_bounds__(512) void k_bucket(const int* __restrict__ src,
                                                const int* __restrict__ dst, int E,
                                                int* __restrict__ wcur, int* __restrict__ packed) {
    __shared__ int h[256];
    __shared__ int base[256];
    int t = threadIdx.x;
    if (t < 256) h[t] = 0;
    __syncthreads();
    int b0 = blockIdx.x * CH;
    int cnt = min(CH, E - b0);
    if (cnt == CH) { // full chunk: int4 paths
        const int4* d4 = (const int4*)(dst + b0);
        for (int i = t; i < CH / 4; i += 512) {
            int4 v = d4[i];
            atomicAdd(&h[v.x / NW], 1); atomicAdd(&h[v.y / NW], 1);
            atomicAdd(&h[v.z / NW], 1); atomicAdd(&h[v.w / NW], 1);
        }
    } else {
        for (int i = t; i < cnt; i += 512) atomicAdd(&h[dst[b0 + i] / NW], 1);
    }
    __syncthreads();
    if (t < 256) { base[t] = atomicAdd(&wcur[t], h[t]); h[t] = 0; }
    __syncthreads();
    if (cnt == CH) {
        const int4* d4 = (const int4*)(dst + b0);
        const int4* s4 = (const int4*)(src + b0);
        for (int i = t; i < CH / 4; i += 512) { // L1/L2-hot re-read
            int4 dv = d4[i];
            int4 sv = s4[i];
            int da[4] = {dv.x, dv.y, dv.z, dv.w};
            int sa[4] = {sv.x, sv.y, sv.z, sv.w};
#pragma unroll
            for (int j = 0; j < 4; ++j) {
                int w = da[j] / NW;
                int l = da[j] - w * NW;
                int r = atomicAdd(&h[w], 1);
                int pos = base[w] + r;
                if (pos < CAP_B) packed[w * CAP_B + pos] = (l << 17) | sa[j];
            }
        }
    } else {
        for (int i = t; i < cnt; i += 512) {
            int d = dst[b0 + i];
            int s = src[b0 + i];
            int w = d / NW;
            int l = d - w * NW;
            int r = atomicAdd(&h[w], 1);
            int pos = base[w] + r;
            if (pos < CAP_B) packed[w * CAP_B + pos] = (l << 17) | s;
        }
    }
}

// -------- fused per-window: degree->norm, shfl-scan, LDS-staged CSR, bf16 prep --------
// CSR is scattered into LDS (cheap random writes) then streamed to global with
// coalesced int4 stores -- removes ~2.4M scattered 4B global writes (partial-line
// RMW in L2) that the old version paid. Also zeros gsum (fold memset).

__global__ __launch_bounds__(512) void k_window(const int* __restrict__ packed,
                                                const int* __restrict__ wcur,
                                                const float4* __restrict__ x4,
                                                float* __restrict__ norm,
                                                int2* __restrict__ rng,
                                                int* __restrict__ csr,
                                                uint4* __restrict__ hb,
                                                float* __restrict__ gsum,
                                                int N, int W, int G) {
    __shared__ int hist[NW];
    __shared__ float snorm[NW];
    __shared__ int pend[NW];    // LDS-relative end
    __shared__ int cur[NW];     // LDS-relative cursor
    __shared__ int wpart[8];
    __shared__ int stot;
    __shared__ __align__(16) int lcsr[CAP_C];  // 40 KB staging
    int t = threadIdx.x, w = blockIdx.x;
    int lo = w * NW, nwn = min(NW, N - lo);
    // fold: zero gsum (grid covers G*64 floats in one stride)
    {
        int i = w * 512 + t;
        if (i < G * 64) gsum[i] = 0.f;
    }
    for (int i = t; i < NW; i += 512) hist[i] = 0;
    __syncthreads();
    int cnt = min(wcur[w], CAP_B);
    const int* pk = packed + (size_t)w * CAP_B;
    for (int e = t; e < cnt; e += 512) atomicAdd(&hist[pk[e] >> 17], 1);
    __syncthreads();
    int d = (t < nwn) ? hist[t] : 0;
    float nv = rsqrtf((float)(d + 1));
    if (t < nwn) { snorm[t] = nv; norm[lo + t] = nv; }
    int pd = (t < nwn) ? ((d + 7) & ~7) : 0; // pad node list to multiple of 8
    // inclusive scan of pd over 512 threads: wave shfl + cross-wave partials
    int lane = t & 63, wid = t >> 6;
    int v = pd;
#pragma unroll
    for (int s = 1; s < 64; s <<= 1) {
        int u = __shfl_up(v, s, 64);
        if (lane >= s) v += u;
    }
    if (lane == 63) wpart[wid] = v;
    __syncthreads();
    if (t < 8) {
        int z = wpart[t];
#pragma unroll
        for (int s = 1; s < 8; s <<= 1) {
            int u = __shfl_up(z, s, 8);
            if (t >= s) z += u;
        }
        wpart[t] = z;
    }
    __syncthreads();
    int incl = v + (wid ? wpart[wid - 1] : 0);
    int gbase = w * CAP_C;
    if (t < nwn) {
        rng[lo + t] = make_int2(gbase + incl - pd, gbase + incl);
        pend[t] = incl;
        cur[t] = incl - pd;
    }
    if (t == 511) stot = incl; // block total (pd=0 for t>=nwn)
    if (w == W - 1 && t == 0) { norm[N] = 1.f; rng[N] = make_int2(0, 0); } // sentinel
    __syncthreads();
    for (int e = t; e < cnt; e += 512) {
        int p = pk[e];
        int pos = atomicAdd(&cur[p >> 17], 1);
        lcsr[pos] = p & 0x1FFFF;
    }
    __syncthreads();
    if (t < nwn) {
        for (int pos = cur[t]; pos < pend[t]; ++pos) lcsr[pos] = N; // sentinel padding
    }
    __syncthreads();
    // stream staged CSR to global, coalesced (tot is a multiple of 8)
    {
        int tot4 = stot >> 2;
        int4* g4 = (int4*)(csr + gbase);
        const int4* l4 = (const int4*)lcsr;
        for (int i = t; i < tot4; i += 512) g4[i] = l4[i];
    }
    // fused prep: hs = norm*x rows in bf16, 4 lanes/row, uint4 stores
    for (int idx = t; idx < nwn * 4; idx += 512) {
        int node = idx >> 2, q = idx & 3;
        float nn = snorm[node];
        float4 va = x4[(size_t)(lo + node) * 8 + q * 2];
        float4 vb = x4[(size_t)(lo + node) * 8 + q * 2 + 1];
        hb[(size_t)(lo + node) * 4 + q] =
            make_uint4(pack2(va.x * nn, va.y * nn), pack2(va.z * nn, va.w * nn),
                       pack2(vb.x * nn, vb.y * nn), pack2(vb.z * nn, vb.w * nn));
    }
    if (w == W - 1 && t < 4) hb[(size_t)N * 4 + t] = make_uint4(0u, 0u, 0u, 0u); // sentinel
}

// Gather hop: 4 lanes/node, uint4 (8 bf16, 16 B) per lane, 16 outstanding gathers.
// Edge lists padded to multiples of 8. csr reads nontemporal (don't evict table).
// Accumulate f32; write bf16 hs = n^2*(sum+self).
__global__ void k_hop(const uint4* __restrict__ tab, const float* __restrict__ norm,
                      const int2* __restrict__ rng, const int* __restrict__ csr,
                      uint4* __restrict__ outb, int N) {
    int group = (blockIdx.x * blockDim.x + threadIdx.x) >> 2; // node id, [0, N]
    int l = threadIdx.x & 3;
    if (group > N) return;
    uint4 sv = tab[(size_t)group * 4 + l]; // self term
    float a0 = lo_f(sv.x), a1 = hi_f(sv.x), a2 = lo_f(sv.y), a3 = hi_f(sv.y);
    float a4 = lo_f(sv.z), a5 = hi_f(sv.z), a6 = lo_f(sv.w), a7 = hi_f(sv.w);
    int2 be = rng[group];
    int k = be.x;
    for (; k + 16 <= be.y; k += 16) {
        int e0 = __builtin_nontemporal_load(csr + k + l);
        int e1 = __builtin_nontemporal_load(csr + k + 4 + l);
        int e2 = __builtin_nontemporal_load(csr + k + 8 + l);
        int e3 = __builtin_nontemporal_load(csr + k + 12 + l);
        uint4 u[16];
#pragma unroll
        for (int j = 0; j < 4; ++j) u[j]      = tab[(size_t)__shfl(e0, j, 4) * 4 + l];
#pragma unroll
        for (int j = 0; j < 4; ++j) u[4 + j]  = tab[(size_t)__shfl(e1, j, 4) * 4 + l];
#pragma unroll
        for (int j = 0; j < 4; ++j) u[8 + j]  = tab[(size_t)__shfl(e2, j, 4) * 4 + l];
#pragma unroll
        for (int j = 0; j < 4; ++j) u[12 + j] = tab[(size_t)__shfl(e3, j, 4) * 4 + l];
#pragma unroll
        for (int j = 0; j < 16; ++j) {
            a0 += lo_f(u[j].x); a1 += hi_f(u[j].x);
            a2 += lo_f(u[j].y); a3 += hi_f(u[j].y);
            a4 += lo_f(u[j].z); a5 += hi_f(u[j].z);
            a6 += lo_f(u[j].w); a7 += hi_f(u[j].w);
        }
    }
    if (k < be.y) { // one remaining 8-group
        int e0 = __builtin_nontemporal_load(csr + k + l);
        int e1 = __builtin_nontemporal_load(csr + k + 4 + l);
        uint4 u[8];
#pragma unroll
        for (int j = 0; j < 4; ++j) u[j]     = tab[(size_t)__shfl(e0, j, 4) * 4 + l];
#pragma unroll
        for (int j = 0; j < 4; ++j) u[4 + j] = tab[(size_t)__shfl(e1, j, 4) * 4 + l];
#pragma unroll
        for (int j = 0; j < 8; ++j) {
            a0 += lo_f(u[j].x); a1 += hi_f(u[j].x);
            a2 += lo_f(u[j].y); a3 += hi_f(u[j].y);
            a4 += lo_f(u[j].z); a5 += hi_f(u[j].z);
            a6 += lo_f(u[j].w); a7 += hi_f(u[j].w);
        }
    }
    float n = norm[group];
    float sc = n * n;
    outb[(size_t)group * 4 + l] = make_uint4(pack2(a0 * sc, a1 * sc), pack2(a2 * sc, a3 * sc),
                                             pack2(a4 * sc, a5 * sc), pack2(a6 * sc, a7 * sc));
}

// Last hop fused with GCN linear + ReLU + per-graph z-sum, 4-lane/node layout.
// Feature k broadcast from sibling lane via shfl width 4; each lane computes 16
// output channels via 4x ds_read_b128 from wT[32][64] (same-address broadcast).
// Reduction: __shfl_xor over node bits {4,8,16,32}, per-wave park, cross-wave sum,
// one global f32 atomicAdd/channel/block-graph.
__global__ __launch_bounds__(256) void k_hopfeat(const uint4* __restrict__ tab,
                                                 const float* __restrict__ norm,
                                                 const int2* __restrict__ rng,
                                                 const int* __restrict__ csr,
                                                 const int* __restrict__ batch,
                                                 const float* __restrict__ gw,
                                                 const float* __restrict__ gb,
                                                 float* __restrict__ gsum, int N) {
    __shared__ __align__(16) float wT[32][64]; // element (k,c) at wT[k][c]
    __shared__ float bs[64];
    __shared__ float accw[4][64];  // per-wave channel sums
    int t = threadIdx.x;
    int wid = t >> 6;
    {   // swizzled init: c = t&63 (banks 0..31 x2), k = 4*iter + wid
        int c = t & 63;
#pragma unroll
        for (int iter = 0; iter < 8; ++iter) {
            int k = iter * 4 + wid;
            wT[k][c] = gw[c * 32 + k];
        }
    }
    if (t < 64) bs[t] = gb[t];
    __syncthreads();
    int group = (blockIdx.x * 256 + t) >> 2; // node id
    int l = t & 3;
    float a[8] = {0.f, 0.f, 0.f, 0.f, 0.f, 0.f, 0.f, 0.f};
    if (group <= N) {
        uint4 sv = tab[(size_t)group * 4 + l]; // self term
        a[0] = lo_f(sv.x); a[1] = hi_f(sv.x); a[2] = lo_f(sv.y); a[3] = hi_f(sv.y);
        a[4] = lo_f(sv.z); a[5] = hi_f(sv.z); a[6] = lo_f(sv.w); a[7] = hi_f(sv.w);
        int2 be = rng[group];
        int k = be.x;
        for (; k + 16 <= be.y; k += 16) {
            int e0 = __builtin_nontemporal_load(csr + k + l);
            int e1 = __builtin_nontemporal_load(csr + k + 4 + l);
            int e2 = __builtin_nontemporal_load(csr + k + 8 + l);
            int e3 = __builtin_nontemporal_load(csr + k + 12 + l);
            uint4 u[16];
#pragma unroll
            for (int j = 0; j < 4; ++j) u[j]      = tab[(size_t)__shfl(e0, j, 4) * 4 + l];
#pragma unroll
            for (int j = 0; j < 4; ++j) u[4 + j]  = tab[(size_t)__shfl(e1, j, 4) * 4 + l];
#pragma unroll
            for (int j = 0; j < 4; ++j) u[8 + j]  = tab[(size_t)__shfl(e2, j, 4) * 4 + l];
#pragma unroll
            for (int j = 0; j < 4; ++j) u[12 + j] = tab[(size_t)__shfl(e3, j, 4) * 4 + l];
#pragma unroll
            for (int j = 0; j < 16; ++j) {
                a[0] += lo_f(u[j].x); a[1] += hi_f(u[j].x);
                a[2] += lo_f(u[j].y); a[3] += hi_f(u[j].y);
                a[4] += lo_f(u[j].z); a[5] += hi_f(u[j].z);
                a[6] += lo_f(u[j].w); a[7] += hi_f(u[j].w);
            }
        }
        if (k < be.y) {
            int e0 = __builtin_nontemporal_load(csr + k + l);
            int e1 = __builtin_nontemporal_load(csr + k + 4 + l);
            uint4 u[8];
#pragma unroll
            for (int j = 0; j < 4; ++j) u[j]     = tab[(size_t)__shfl(e0, j, 4) * 4 + l];
#pragma unroll
            for (int j = 0; j < 4; ++j) u[4 + j] = tab[(size_t)__shfl(e1, j, 4) * 4 + l];
#pragma unroll
            for (int j = 0; j < 8; ++j) {
                a[0] += lo_f(u[j].x); a[1] += hi_f(u[j].x);
                a[2] += lo_f(u[j].y); a[3] += hi_f(u[j].y);
                a[4] += lo_f(u[j].z); a[5] += hi_f(u[j].z);
                a[6] += lo_f(u[j].w); a[7] += hi_f(u[j].w);
            }
        }
        float n = norm[group];
#pragma unroll
        for (int j = 0; j < 8; ++j) a[j] *= n; // final h (f32, pre-rounding)
    }
    float o[16];
#pragma unroll
    for (int cc = 0; cc < 16; ++cc) o[cc] = 0.f;
    int gmy = 0x7fffffff; // lanes without a real node never match any graph
    if (group < N) {      // uniform across each 4-lane cluster -> shfl safe
        gmy = batch[group];
        float dd[16];
#pragma unroll
        for (int cc = 0; cc < 16; ++cc) dd[cc] = bs[l * 16 + cc];
#pragma unroll
        for (int k = 0; k < 32; ++k) {
            float hk = __shfl(a[k & 7], k >> 3, 4); // feature k from sibling lane
            const float4* wv = (const float4*)&wT[k][l * 16];
            float4 w0 = wv[0], w1 = wv[1], w2 = wv[2], w3 = wv[3];
            dd[0]  += hk * w0.x; dd[1]  += hk * w0.y; dd[2]  += hk * w0.z; dd[3]  += hk * w0.w;
            dd[4]  += hk * w1.x; dd[5]  += hk * w1.y; dd[6]  += hk * w1.z; dd[7]  += hk * w1.w;
            dd[8]  += hk * w2.x; dd[9]  += hk * w2.y; dd[10] += hk * w2.z; dd[11] += hk * w2.w;
            dd[12] += hk * w3.x; dd[13] += hk * w3.y; dd[14] += hk * w3.z; dd[15] += hk * w3.w;
        }
#pragma unroll
        for (int cc = 0; cc < 16; ++cc) o[cc] = fmaxf(dd[cc], 0.f);
    }
    // per-graph reduction (tile spans [g0, g1], usually 1-2 graphs)
    int n0 = blockIdx.x * 64;
    int g0 = batch[min(n0, N - 1)];
    int g1 = batch[min(n0 + 63, N - 1)];
    bool leader = (t & 0x3C) == 0; // node-within-wave == 0 (4 lanes/cluster)
    for (int g = g0; g <= g1; ++g) {
        float v[16];
#pragma unroll
        for (int cc = 0; cc < 16; ++cc) {
            float val = (gmy == g) ? o[cc] : 0.f;
            val += __shfl_xor(val, 4, 64);   // butterflies over node bits: l preserved
            val += __shfl_xor(val, 8, 64);
            val += __shfl_xor(val, 16, 64);
            val += __shfl_xor(val, 32, 64);
            v[cc] = val;
        }
        if (leader) {
#pragma unroll
            for (int cc = 0; cc < 16; ++cc) accw[wid][l * 16 + cc] = v[cc];
        }
        __syncthreads();
        if (t < 64) {
            float s = accw[0][t] + accw[1][t] + accw[2][t] + accw[3][t];
            if (s != 0.f) atomicAdd(&gsum[(size_t)g * 64 + t], s);
        }
        __syncthreads();
    }
}

// ---------------- mean + classifier head, one block (64 thr) per graph ----------------

__global__ __launch_bounds__(64) void k_head(const float* __restrict__ gsum,
                                             const int* __restrict__ batch, int N,
                                             const float* __restrict__ w1, const float* __restrict__ b1,
                                             const float* __restrict__ w2, const float* __restrict__ b2,
                                             float* __restrict__ out) {
    __shared__ float havg[64];
    __shared__ float h1s[32];
    __shared__ int se[2];
    int t = threadIdx.x, g = blockIdx.x;
    if (t < 2) { // lower_bound(batch, g) / lower_bound(batch, g+1)
        int target = g + t;
        int lo = 0, hi = N;
        while (lo < hi) { int mid = (lo + hi) >> 1; if (batch[mid] < target) lo = mid + 1; else hi = mid; }
        se[t] = lo;
    }
    __syncthreads();
    int cnt = se[1] - se[0];
    float inv = 1.f / (float)(cnt > 0 ? cnt : 1);
    havg[t] = gsum[(size_t)g * 64 + t] * inv;
    __syncthreads();
    if (t < 32) {
        float d = b1[t];
#pragma unroll
        for (int k = 0; k < 64; ++k) d += havg[k] * w1[t * 64 + k];
        h1s[t] = fmaxf(d, 0.f);
    }
    __syncthreads();
    if (t < 16) {
        float d = b2[t];
#pragma unroll
        for (int j = 0; j < 32; ++j) d += h1s[j] * w2[t * 32 + j];
        out[g * 16 + t] = d;
    }
}

// ---------------- launch ----------------

extern "C" void kernel_launch(void* const* d_in, const int* in_sizes, int n_in,
                              void* d_out, int out_size, void* d_ws, size_t ws_size,
                              hipStream_t stream) {
    const float* x     = (const float*)d_in[0];
    const int*   ei    = (const int*)d_in[1];
    const int*   batch = (const int*)d_in[2];
    const float* gw    = (const float*)d_in[3];
    const float* gb    = (const float*)d_in[4];
    const float* w1    = (const float*)d_in[5];
    const float* b1    = (const float*)d_in[6];
    const float* w2    = (const float*)d_in[7];
    const float* b2    = (const float*)d_in[8];
    float* out = (float*)d_out;

    int N = in_sizes[2];
    int E = in_sizes[1] / 2;
    int G = out_size / 16;
    const int* srcp = ei;
    const int* dstp = ei + E;

    int W  = (N + NW - 1) / NW;   // 256
    int NB = (E + CH - 1) / CH;   // 250

    char* ws = (char*)d_ws;
    size_t off = 0;
    auto alloc = [&](size_t bytes) -> void* {
        void* p = ws + off;
        off += (bytes + 255) & ~(size_t)255;
        return p;
    };
    int*   wcur   = (int*)alloc(256 * 4);
    float* gsum   = (float*)alloc((size_t)G * 64 * 4);
    int*   packed = (int*)alloc((size_t)W * CAP_B * 4);          // 8 MB
    int*   csr    = (int*)alloc((size_t)W * CAP_C * 4);          // 10.5 MB
    int2*  rng    = (int2*)alloc((size_t)(N + 1) * 8);
    float* norm   = (float*)alloc((size_t)(N + 1) * 4);
    uint4* hbA    = (uint4*)alloc((size_t)(N + 1) * 64);         // bf16 table A
    uint4* hbB    = (uint4*)alloc((size_t)(N + 1) * 64);         // bf16 table B

    hipMemsetAsync(wcur, 0, 256 * 4, stream); // gsum zeroed inside k_window

    int pb4 = ((N + 1) * 4 + 255) / 256; // 4 lanes per node

    k_bucket<<<NB, 512, 0, stream>>>(srcp, dstp, E, wcur, packed);
    k_window<<<W, 512, 0, stream>>>(packed, wcur, (const float4*)x, norm, rng, csr,
                                    hbA, gsum, N, W, G);

    k_hop<<<pb4, 256, 0, stream>>>(hbA, norm, rng, csr, hbB, N);
    k_hop<<<pb4, 256, 0, stream>>>(hbB, norm, rng, csr, hbA, N);
    k_hopfeat<<<pb4, 256, 0, stream>>>(hbA, norm, rng, csr, batch, gw, gb, gsum, N);

    k_head<<<G, 64, 0, stream>>>(gsum, batch, N, w1, b1, w2, b2, out);
}